// Round 2
// baseline (1437.494 us; speedup 1.0000x reference)
//
#include <hip/hip_runtime.h>

// TimestepNorm: B=16, L=4096, D=1024, fp32 — single-pass decoupled lookback.
//
// One kernel: each block owns one (b, c) chunk of 32 rows.
//  1. dynamic ticket (atomicAdd) -> (b, c); ticket order == start order, so a
//     waiting block's predecessors have always already started; they publish
//     their aggregate (flag=1) with no cross-block waits -> no deadlock.
//  2. local Welford over the chunk (x read from HBM once, coalesced float4).
//  3. publish per-chunk aggregate payload (contiguous [chunk][d4] layout),
//     per-thread __threadfence, then flag=1 via atomicExch (RMW release).
//  4. lookback: THREAD 0 ONLY polls pred flags via atomicAdd(p,0) RMW
//     (coherence-point read — immune to stale per-XCD L2 lines), walks back
//     through flag==1 chunks until a flag==2 inclusive prefix (or c==0 ->
//     prev carry). Decision broadcast via LDS; all threads __threadfence
//     (L2 inv) then bulk-merge the aggregate payloads (coalesced).
//  5. publish inclusive prefix, flag=2 (unblocks successors BEFORE emit);
//     last chunk writes count/mean/var outputs.
//  6. emit: replay chunk rows from exclusive prefix; x re-read is L3-hot.
//
// Replay safety: ticket masked into [0,NCH) — a stale re-execution (rocprof
// dispatch replay without tn_init) stays in-bounds and terminates instantly
// on leftover flags=2. Flags live in poisoned workspace -> init kernel zeroes.

#define Bn 16
#define Ln 4096
#define Dn 1024
#define D4 (Dn / 4)     // 256 float4 groups
#define Cn 128
#define CLn (Ln / Cn)   // 32 rows per chunk
#define NCH (Bn * Cn)   // 2048 chunks
#define EPSf 1e-5f

struct St { float n; float4 m; float4 s; };   // count, mean, M2 (= n*var)

__device__ __forceinline__ St chan_merge(const St& A, const St& B) {
    St R;
    R.n = A.n + B.n;
    float wB = B.n / fmaxf(R.n, 1.f);          // identity-safe: n==0 on either side
    float sc = A.n * wB;
    float dx = B.m.x - A.m.x, dy = B.m.y - A.m.y,
          dz = B.m.z - A.m.z, dw = B.m.w - A.m.w;
    R.m.x = A.m.x + dx * wB; R.m.y = A.m.y + dy * wB;
    R.m.z = A.m.z + dz * wB; R.m.w = A.m.w + dw * wB;
    R.s.x = A.s.x + B.s.x + dx * dx * sc; R.s.y = A.s.y + B.s.y + dy * dy * sc;
    R.s.z = A.s.z + B.s.z + dz * dz * sc; R.s.w = A.s.w + B.s.w + dw * dw * sc;
    return R;
}

__global__ __launch_bounds__(256) void tn_init(int* __restrict__ flags,
                                               int* __restrict__ ticket)
{
    int i = threadIdx.x;
    #pragma unroll
    for (int k = 0; k < NCH / 256; ++k) flags[k * 256 + i] = 0;
    if (i == 0) *ticket = 0;
}

__global__ __launch_bounds__(256) void tn_fused(
    const float* __restrict__ x, const int* __restrict__ mask,
    const int* __restrict__ prev_count, const float4* __restrict__ prev_mean,
    const float4* __restrict__ prev_var,
    const float* __restrict__ weight, const float* __restrict__ bias,
    float4* __restrict__ agg_mean, float4* __restrict__ agg_m2,
    float4* __restrict__ pref_mean, float4* __restrict__ pref_m2,
    float* __restrict__ agg_n, float* __restrict__ pref_n,
    int* __restrict__ flags, int* __restrict__ ticket,
    float* __restrict__ y, float* __restrict__ out_count,
    float4* __restrict__ out_mean, float4* __restrict__ out_var)
{
    __shared__ int s_vt, s_stop, s_mode;
    if (threadIdx.x == 0) s_vt = atomicAdd(ticket, 1) & (NCH - 1);
    __syncthreads();
    int vt = s_vt;
    int c  = vt >> 4;            // chunk index along L: low c gets early tickets
    int b  = vt & (Bn - 1);      // 16 chains advance in parallel
    int ch = b * Cn + c;
    int d4 = threadIdx.x;

    size_t gbase = ((size_t)b * Ln + (size_t)c * CLn) * Dn;
    const float4* xp = (const float4*)(x + gbase) + d4;
    const int*    mp = mask + b * Ln + c * CLn;

    // ---- phase 1: local chunk Welford -------------------------------------
    St A; A.n = 0.f; A.m = {0.f, 0.f, 0.f, 0.f}; A.s = {0.f, 0.f, 0.f, 0.f};
    #pragma unroll 8
    for (int i = 0; i < CLn; ++i) {
        float4 xv = xp[(size_t)i * D4];        // unconditional: keep MLP deep
        if (mp[i] == 0) {                      // block-uniform branch
            A.n += 1.f;
            float rn = 1.f / A.n;
            float dx;
            dx = xv.x - A.m.x; A.m.x += dx * rn; A.s.x += dx * (xv.x - A.m.x);
            dx = xv.y - A.m.y; A.m.y += dx * rn; A.s.y += dx * (xv.y - A.m.y);
            dx = xv.z - A.m.z; A.m.z += dx * rn; A.s.z += dx * (xv.z - A.m.z);
            dx = xv.w - A.m.w; A.m.w += dx * rn; A.s.w += dx * (xv.w - A.m.w);
        }
    }

    // ---- phase 2: publish aggregate (contiguous per-chunk payload) --------
    agg_mean[(size_t)ch * D4 + d4] = A.m;
    agg_m2  [(size_t)ch * D4 + d4] = A.s;
    if (threadIdx.x == 0) agg_n[ch] = A.n;
    __threadfence();                           // each thread flushes its stores
    __syncthreads();
    if (threadIdx.x == 0) atomicExch(&flags[ch], 1);   // RMW release

    // ---- phase 3: lookback decision (thread 0), bulk merge (all) ----------
    if (threadIdx.x == 0) {
        int look = c - 1, mode = 0;            // mode 0: prev carry, 1: pref
        while (look >= 0) {
            int f = atomicAdd(&flags[b * Cn + look], 0);  // coherent RMW read
            if (f == 0) { __builtin_amdgcn_s_sleep(2); continue; }
            if (f == 2) { mode = 1; break; }
            --look;                            // f==1: merge its aggregate later
        }
        s_stop = look; s_mode = mode;
    }
    __syncthreads();
    __threadfence();                           // acquire: drop stale L1/L2 lines
    int stop = s_stop, mode = s_mode;

    St E;
    if (mode == 1) {                           // base = inclusive prefix at stop
        E.n = pref_n[b * Cn + stop];
        E.m = pref_mean[(size_t)(b * Cn + stop) * D4 + d4];
        E.s = pref_m2  [(size_t)(b * Cn + stop) * D4 + d4];
    } else {                                   // base = prev carry (stop == -1)
        E.n = (float)prev_count[b];            // >= 1 always
        E.m = prev_mean[b * D4 + d4];
        float4 vp = prev_var[b * D4 + d4];
        E.s = {vp.x * E.n, vp.y * E.n, vp.z * E.n, vp.w * E.n};
    }
    for (int l = stop + 1; l < c; ++l) {       // ascending aggregate merges
        St ag;
        ag.n = agg_n[b * Cn + l];
        ag.m = agg_mean[(size_t)(b * Cn + l) * D4 + d4];
        ag.s = agg_m2  [(size_t)(b * Cn + l) * D4 + d4];
        E = chan_merge(E, ag);
    }

    // ---- phase 4: publish inclusive prefix ASAP (unblocks successors) -----
    St I = chan_merge(E, A);
    pref_mean[(size_t)ch * D4 + d4] = I.m;
    pref_m2  [(size_t)ch * D4 + d4] = I.s;
    if (threadIdx.x == 0) pref_n[ch] = I.n;
    __threadfence();
    __syncthreads();
    if (threadIdx.x == 0) atomicExch(&flags[ch], 2);   // RMW release

    if (c == Cn - 1) {                         // final running stats outputs
        out_mean[b * D4 + d4] = I.m;
        float rn = 1.f / I.n;
        out_var[b * D4 + d4] = {I.s.x * rn, I.s.y * rn, I.s.z * rn, I.s.w * rn};
        if (threadIdx.x == 0) out_count[b] = I.n;
    }

    // ---- phase 5: emit (x re-read is L3-hot; y is the only new HBM) -------
    const float4 w4 = ((const float4*)weight)[d4];
    const float4 b4 = ((const float4*)bias)[d4];
    float gx = w4.x + 1.f, gy = w4.y + 1.f, gz = w4.z + 1.f, gw = w4.w + 1.f;
    float  n    = E.n;
    float4 mean = E.m;
    float4 M2   = E.s;
    float4* yp = (float4*)(y + gbase) + d4;

    #pragma unroll 4
    for (int i = 0; i < CLn; ++i) {
        float4 yv = {0.f, 0.f, 0.f, 0.f};
        if (mp[i] == 0) {                      // block-uniform: skip masked rows
            float4 xv = xp[(size_t)i * D4];
            n += 1.f;
            float rn = 1.f / n;
            float dx, d2;
            dx = xv.x - mean.x; mean.x += dx * rn; d2 = xv.x - mean.x;
            M2.x += dx * d2; yv.x = gx * d2 * rsqrtf(M2.x * rn + EPSf) + b4.x;
            dx = xv.y - mean.y; mean.y += dx * rn; d2 = xv.y - mean.y;
            M2.y += dx * d2; yv.y = gy * d2 * rsqrtf(M2.y * rn + EPSf) + b4.y;
            dx = xv.z - mean.z; mean.z += dx * rn; d2 = xv.z - mean.z;
            M2.z += dx * d2; yv.z = gz * d2 * rsqrtf(M2.z * rn + EPSf) + b4.z;
            dx = xv.w - mean.w; mean.w += dx * rn; d2 = xv.w - mean.w;
            M2.w += dx * d2; yv.w = gw * d2 * rsqrtf(M2.w * rn + EPSf) + b4.w;
        }
        yp[(size_t)i * D4] = yv;
    }
}

extern "C" void kernel_launch(void* const* d_in, const int* in_sizes, int n_in,
                              void* d_out, int out_size, void* d_ws, size_t ws_size,
                              hipStream_t stream)
{
    const float* x          = (const float*)d_in[0];
    const int*   prev_count = (const int*)d_in[1];
    const float* prev_mean  = (const float*)d_in[2];
    const float* prev_var   = (const float*)d_in[3];
    const float* weight     = (const float*)d_in[4];
    const float* bias       = (const float*)d_in[5];
    const int*   mask       = (const int*)d_in[6];   // bool arrives as int32

    // outputs: y [B*L*D], count [B], mean [B*D], var [B*D] (all fp32, concat)
    float* y         = (float*)d_out;
    float* out_count = y + (size_t)Bn * Ln * Dn;
    float* out_mean  = out_count + Bn;
    float* out_var   = out_mean + (size_t)Bn * Dn;

    // workspace (~33.6 MB): 4 payload arrays + counts + flags + ticket
    float4* agg_mean  = (float4*)d_ws;
    float4* agg_m2    = agg_mean  + (size_t)NCH * D4;
    float4* pref_mean = agg_m2    + (size_t)NCH * D4;
    float4* pref_m2   = pref_mean + (size_t)NCH * D4;
    float*  agg_n     = (float*)(pref_m2 + (size_t)NCH * D4);
    float*  pref_n    = agg_n + NCH;
    int*    flags     = (int*)(pref_n + NCH);
    int*    ticket    = flags + NCH;

    tn_init<<<1, 256, 0, stream>>>(flags, ticket);
    tn_fused<<<NCH, 256, 0, stream>>>(
        x, mask, prev_count, (const float4*)prev_mean, (const float4*)prev_var,
        weight, bias,
        agg_mean, agg_m2, pref_mean, pref_m2, agg_n, pref_n, flags, ticket,
        y, out_count, (float4*)out_mean, (float4*)out_var);
}

// Round 4
// 537.841 us; speedup vs baseline: 2.6727x; 2.6727x over previous
//
#include <hip/hip_runtime.h>

// TimestepNorm: B=16, L=4096, D=1024, fp32 — 3-kernel chunk-scan, no atomics.
// K1: per-chunk Welford (2048 blocks, skip masked rows -> ~134MB x read).
// K2: segmented chain scan, 64 blocks x 256 thr; thread owns one (b,d4) chain
//     quarter (32 chunks); LDS scan joins quarters. All payload I/O is 1KB-
//     contiguous per wave (layout [chunk][d4], NOT transposed).
// K3: replay chunk from exclusive prefix, emit y. x re-read is L3-candidate
//     (valid x ~134MB + stats ~50MB < 256MB L3).
// No atomics / spin loops anywhere: nothing can deadlock, replay-safe.

#define Bn 16
#define Ln 4096
#define Dn 1024
#define D4 (Dn / 4)     // 256 float4 groups
#define Cn 128
#define CLn (Ln / Cn)   // 32 rows per chunk
#define NCH (Bn * Cn)   // 2048 chunks
#define SEG 32          // chunks per K2 segment (4 segments per chain)
#define EPSf 1e-5f

struct St { float n; float4 m; float4 s; };   // count, mean, M2 (= n*var)

__device__ __forceinline__ St chan_merge(const St& A, const St& B) {
    St R;
    R.n = A.n + B.n;
    float wB = B.n / fmaxf(R.n, 1.f);          // identity-safe: n==0 on either side
    float sc = A.n * wB;
    float dx = B.m.x - A.m.x, dy = B.m.y - A.m.y,
          dz = B.m.z - A.m.z, dw = B.m.w - A.m.w;
    R.m.x = A.m.x + dx * wB; R.m.y = A.m.y + dy * wB;
    R.m.z = A.m.z + dz * wB; R.m.w = A.m.w + dw * wB;
    R.s.x = A.s.x + B.s.x + dx * dx * sc; R.s.y = A.s.y + B.s.y + dy * dy * sc;
    R.s.z = A.s.z + B.s.z + dz * dz * sc; R.s.w = A.s.w + B.s.w + dw * dw * sc;
    return R;
}

// ---- K1: per-chunk Welford --------------------------------------------------
__global__ __launch_bounds__(256) void tn_chunk_stats(
    const float* __restrict__ x, const int* __restrict__ mask,
    float4* __restrict__ agg_mean, float4* __restrict__ agg_m2,
    float* __restrict__ agg_n)
{
    int bc = blockIdx.x;                      // b*Cn + c  (Ln == Cn*CLn)
    int d4 = threadIdx.x;
    const float4* xp = (const float4*)(x + (size_t)bc * CLn * Dn) + d4;
    const int4*   mp = (const int4*)(mask + bc * CLn);

    int4 mrow[CLn / 4];
    #pragma unroll
    for (int i = 0; i < CLn / 4; ++i) mrow[i] = mp[i];
    const int* mr = (const int*)mrow;

    St A; A.n = 0.f; A.m = {0.f, 0.f, 0.f, 0.f}; A.s = {0.f, 0.f, 0.f, 0.f};
    #pragma unroll 8
    for (int i = 0; i < CLn; ++i) {
        if (mr[i] == 0) {                     // block-uniform; masked rows never read
            float4 xv = xp[(size_t)i * D4];
            A.n += 1.f;
            float rn = 1.f / A.n;
            float dx;
            dx = xv.x - A.m.x; A.m.x += dx * rn; A.s.x += dx * (xv.x - A.m.x);
            dx = xv.y - A.m.y; A.m.y += dx * rn; A.s.y += dx * (xv.y - A.m.y);
            dx = xv.z - A.m.z; A.m.z += dx * rn; A.s.z += dx * (xv.z - A.m.z);
            dx = xv.w - A.m.w; A.m.w += dx * rn; A.s.w += dx * (xv.w - A.m.w);
        }
    }
    agg_mean[(size_t)bc * D4 + d4] = A.m;     // contiguous 4KB per chunk
    agg_m2  [(size_t)bc * D4 + d4] = A.s;
    if (d4 == 0) agg_n[bc] = A.n;
}

// ---- K2: segmented chain scan ----------------------------------------------
// grid 64 = 16 b x 4 d4-groups; block 256 = 64 d4 x 4 segments (wave == segment)
__global__ __launch_bounds__(256) void tn_scan(
    const int* __restrict__ prev_count, const float4* __restrict__ prev_mean,
    const float4* __restrict__ prev_var,
    const float4* __restrict__ agg_mean, const float4* __restrict__ agg_m2,
    const float* __restrict__ agg_n,
    float4* __restrict__ pref_mean, float4* __restrict__ pref_m2,
    float* __restrict__ pref_n,
    float* __restrict__ out_count, float4* __restrict__ out_mean,
    float4* __restrict__ out_var)
{
    __shared__ St lds[4][64];                 // 48B-stride rows, 12 KiB total
    int g   = blockIdx.x & 3;
    int b   = blockIdx.x >> 2;
    int d4l = threadIdx.x & 63;
    int q   = threadIdx.x >> 6;               // wave index == segment
    int d4  = g * 64 + d4l;
    int c0  = q * SEG;

    // pass 1: local segment aggregate (1KB-contiguous loads per wave)
    St S; S.n = 0.f; S.m = {0.f, 0.f, 0.f, 0.f}; S.s = {0.f, 0.f, 0.f, 0.f};
    #pragma unroll 4
    for (int i = 0; i < SEG; ++i) {
        int ch = b * Cn + c0 + i;
        St ag;
        ag.n = agg_n[ch];                     // uniform addr -> broadcast
        ag.m = agg_mean[(size_t)ch * D4 + d4];
        ag.s = agg_m2  [(size_t)ch * D4 + d4];
        S = chan_merge(S, ag);
    }
    lds[q][d4l] = S;
    __syncthreads();

    // exclusive base for this segment: prev carry + earlier segments
    St E;
    E.n = (float)prev_count[b];               // >= 1 always
    E.m = prev_mean[b * D4 + d4];
    float4 vp = prev_var[b * D4 + d4];
    E.s = {vp.x * E.n, vp.y * E.n, vp.z * E.n, vp.w * E.n};
    #pragma unroll
    for (int j = 0; j < 3; ++j)
        if (j < q) E = chan_merge(E, lds[j][d4l]);

    // pass 2: replay segment, write exclusive prefix per chunk (L2-hot reads)
    #pragma unroll 4
    for (int i = 0; i < SEG; ++i) {
        int ch = b * Cn + c0 + i;
        pref_mean[(size_t)ch * D4 + d4] = E.m;
        pref_m2  [(size_t)ch * D4 + d4] = E.s;
        if (d4 == 0) pref_n[ch] = E.n;
        St ag;
        ag.n = agg_n[ch];
        ag.m = agg_mean[(size_t)ch * D4 + d4];
        ag.s = agg_m2  [(size_t)ch * D4 + d4];
        E = chan_merge(E, ag);
    }

    if (q == 3) {                             // E is now the inclusive total
        out_mean[b * D4 + d4] = E.m;
        float rn = 1.f / E.n;
        out_var[b * D4 + d4] = {E.s.x * rn, E.s.y * rn, E.s.z * rn, E.s.w * rn};
        if (d4 == 0) out_count[b] = E.n;
    }
}

// ---- K3: replay + emit ------------------------------------------------------
__global__ __launch_bounds__(256) void tn_emit(
    const float* __restrict__ x, const int* __restrict__ mask,
    const float* __restrict__ weight, const float* __restrict__ bias,
    const float4* __restrict__ pref_mean, const float4* __restrict__ pref_m2,
    const float* __restrict__ pref_n, float* __restrict__ y)
{
    int bc = blockIdx.x;
    int d4 = threadIdx.x;
    size_t gbase = (size_t)bc * CLn * Dn;
    const float4* xp = (const float4*)(x + gbase) + d4;
    float4*       yp = (float4*)(y + gbase) + d4;
    const int4*   mp = (const int4*)(mask + bc * CLn);

    int4 mrow[CLn / 4];
    #pragma unroll
    for (int i = 0; i < CLn / 4; ++i) mrow[i] = mp[i];
    const int* mr = (const int*)mrow;

    float  n    = pref_n[bc];
    float4 mean = pref_mean[(size_t)bc * D4 + d4];   // contiguous
    float4 M2   = pref_m2  [(size_t)bc * D4 + d4];
    const float4 w4 = ((const float4*)weight)[d4];
    const float4 b4 = ((const float4*)bias)[d4];
    float gx = w4.x + 1.f, gy = w4.y + 1.f, gz = w4.z + 1.f, gw = w4.w + 1.f;

    #pragma unroll 4
    for (int i = 0; i < CLn; ++i) {
        float4 yv = {0.f, 0.f, 0.f, 0.f};
        if (mr[i] == 0) {                     // block-uniform: skip masked rows
            float4 xv = xp[(size_t)i * D4];
            n += 1.f;
            float rn = 1.f / n;
            float dx, d2;
            dx = xv.x - mean.x; mean.x += dx * rn; d2 = xv.x - mean.x;
            M2.x += dx * d2; yv.x = gx * d2 * rsqrtf(M2.x * rn + EPSf) + b4.x;
            dx = xv.y - mean.y; mean.y += dx * rn; d2 = xv.y - mean.y;
            M2.y += dx * d2; yv.y = gy * d2 * rsqrtf(M2.y * rn + EPSf) + b4.y;
            dx = xv.z - mean.z; mean.z += dx * rn; d2 = xv.z - mean.z;
            M2.z += dx * d2; yv.z = gz * d2 * rsqrtf(M2.z * rn + EPSf) + b4.z;
            dx = xv.w - mean.w; mean.w += dx * rn; d2 = xv.w - mean.w;
            M2.w += dx * d2; yv.w = gw * d2 * rsqrtf(M2.w * rn + EPSf) + b4.w;
        }
        yp[(size_t)i * D4] = yv;
    }
}

extern "C" void kernel_launch(void* const* d_in, const int* in_sizes, int n_in,
                              void* d_out, int out_size, void* d_ws, size_t ws_size,
                              hipStream_t stream)
{
    const float* x          = (const float*)d_in[0];
    const int*   prev_count = (const int*)d_in[1];
    const float* prev_mean  = (const float*)d_in[2];
    const float* prev_var   = (const float*)d_in[3];
    const float* weight     = (const float*)d_in[4];
    const float* bias       = (const float*)d_in[5];
    const int*   mask       = (const int*)d_in[6];   // bool arrives as int32

    // outputs: y [B*L*D], count [B], mean [B*D], var [B*D] (all fp32, concat)
    float* y         = (float*)d_out;
    float* out_count = y + (size_t)Bn * Ln * Dn;
    float* out_mean  = out_count + Bn;
    float* out_var   = out_mean + (size_t)Bn * Dn;

    // workspace (~33.6 MB): agg/pref payloads [NCH*D4] float4 + per-chunk n
    float4* agg_mean  = (float4*)d_ws;
    float4* agg_m2    = agg_mean  + (size_t)NCH * D4;
    float4* pref_mean = agg_m2    + (size_t)NCH * D4;
    float4* pref_m2   = pref_mean + (size_t)NCH * D4;
    float*  agg_n     = (float*)(pref_m2 + (size_t)NCH * D4);
    float*  pref_n    = agg_n + NCH;

    tn_chunk_stats<<<NCH, 256, 0, stream>>>(x, mask, agg_mean, agg_m2, agg_n);
    tn_scan<<<64, 256, 0, stream>>>(
        prev_count, (const float4*)prev_mean, (const float4*)prev_var,
        agg_mean, agg_m2, agg_n, pref_mean, pref_m2, pref_n,
        out_count, (float4*)out_mean, (float4*)out_var);
    tn_emit<<<NCH, 256, 0, stream>>>(
        x, mask, weight, bias, pref_mean, pref_m2, pref_n, y);
}

// Round 6
// 502.064 us; speedup vs baseline: 2.8632x; 1.0713x over previous
//
#include <hip/hip_runtime.h>

// TimestepNorm: B=16, L=4096, D=1024, fp32 — 3-kernel chunk-scan, no atomics.
// K1: per-chunk Welford (2048 blocks, skip masked rows -> ~134MB x read),
//     stats written contiguous [chunk][d4] (coalesced 4KB per chunk).
// K2: Kogge-Stone wave scan, ONE WAVE PER (b,d4) CHAIN (4096 waves, 1024
//     blocks — round-4's 64-block segmented scan left 75% of CUs idle).
//     Per-lane 16B gathers at 8KB stride hit L2/L3 (stats are 16.8MB, just
//     written by K1) — amplification is cheap there.
// K3: replay chunk from exclusive prefix, emit y. y stored NONTEMPORAL so the
//     268MB write-once stream doesn't evict x from L3 (valid x ~134MB + stats
//     ~50MB < 256MB L3 -> x re-read stays cache-hot).
// NOTE: __builtin_nontemporal_store needs a NATIVE vector type, not HIP's
// float4 class -> cast through ext_vector_type(4) float.

#define Bn 16
#define Ln 4096
#define Dn 1024
#define D4 (Dn / 4)     // 256 float4 groups
#define Cn 128
#define CLn (Ln / Cn)   // 32 rows per chunk
#define NCH (Bn * Cn)   // 2048 chunks
#define EPSf 1e-5f

typedef float f32x4 __attribute__((ext_vector_type(4)));   // native vec for nt-store

struct St { float n; float4 m; float4 s; };   // count, mean, M2 (= n*var)

__device__ __forceinline__ St chan_merge(const St& A, const St& B) {
    St R;
    R.n = A.n + B.n;
    float wB = B.n / fmaxf(R.n, 1.f);          // identity-safe: n==0 on either side
    float sc = A.n * wB;
    float dx = B.m.x - A.m.x, dy = B.m.y - A.m.y,
          dz = B.m.z - A.m.z, dw = B.m.w - A.m.w;
    R.m.x = A.m.x + dx * wB; R.m.y = A.m.y + dy * wB;
    R.m.z = A.m.z + dz * wB; R.m.w = A.m.w + dw * wB;
    R.s.x = A.s.x + B.s.x + dx * dx * sc; R.s.y = A.s.y + B.s.y + dy * dy * sc;
    R.s.z = A.s.z + B.s.z + dz * dz * sc; R.s.w = A.s.w + B.s.w + dw * dw * sc;
    return R;
}

__device__ __forceinline__ St shfl_up_st(const St& v, int delta) {
    St r;
    r.n   = __shfl_up(v.n,   delta, 64);
    r.m.x = __shfl_up(v.m.x, delta, 64); r.m.y = __shfl_up(v.m.y, delta, 64);
    r.m.z = __shfl_up(v.m.z, delta, 64); r.m.w = __shfl_up(v.m.w, delta, 64);
    r.s.x = __shfl_up(v.s.x, delta, 64); r.s.y = __shfl_up(v.s.y, delta, 64);
    r.s.z = __shfl_up(v.s.z, delta, 64); r.s.w = __shfl_up(v.s.w, delta, 64);
    return r;
}

// ---- K1: per-chunk Welford --------------------------------------------------
__global__ __launch_bounds__(256) void tn_chunk_stats(
    const float* __restrict__ x, const int* __restrict__ mask,
    float4* __restrict__ agg_mean, float4* __restrict__ agg_m2,
    float* __restrict__ agg_n)
{
    int bc = blockIdx.x;                      // b*Cn + c  (Ln == Cn*CLn)
    int d4 = threadIdx.x;
    const float4* xp = (const float4*)(x + (size_t)bc * CLn * Dn) + d4;
    const int4*   mp = (const int4*)(mask + bc * CLn);

    int4 mrow[CLn / 4];
    #pragma unroll
    for (int i = 0; i < CLn / 4; ++i) mrow[i] = mp[i];
    const int* mr = (const int*)mrow;

    St A; A.n = 0.f; A.m = {0.f, 0.f, 0.f, 0.f}; A.s = {0.f, 0.f, 0.f, 0.f};
    #pragma unroll 8
    for (int i = 0; i < CLn; ++i) {
        if (mr[i] == 0) {                     // block-uniform; masked rows never read
            float4 xv = xp[(size_t)i * D4];
            A.n += 1.f;
            float rn = 1.f / A.n;
            float dx;
            dx = xv.x - A.m.x; A.m.x += dx * rn; A.s.x += dx * (xv.x - A.m.x);
            dx = xv.y - A.m.y; A.m.y += dx * rn; A.s.y += dx * (xv.y - A.m.y);
            dx = xv.z - A.m.z; A.m.z += dx * rn; A.s.z += dx * (xv.z - A.m.z);
            dx = xv.w - A.m.w; A.m.w += dx * rn; A.s.w += dx * (xv.w - A.m.w);
        }
    }
    agg_mean[(size_t)bc * D4 + d4] = A.m;     // contiguous 4KB per chunk
    agg_m2  [(size_t)bc * D4 + d4] = A.s;
    if (d4 == 0) agg_n[bc] = A.n;
}

// ---- K2: Kogge-Stone wave scan, one wave per (b,d4) chain -------------------
// 4096 waves = 1024 blocks x 4; lane owns chunk pair (2*lane, 2*lane+1).
__global__ __launch_bounds__(256) void tn_scan(
    const int* __restrict__ prev_count, const float4* __restrict__ prev_mean,
    const float4* __restrict__ prev_var,
    const float4* __restrict__ agg_mean, const float4* __restrict__ agg_m2,
    const float* __restrict__ agg_n,
    float4* __restrict__ pref_mean, float4* __restrict__ pref_m2,
    float* __restrict__ pref_n,
    float* __restrict__ out_count, float4* __restrict__ out_mean,
    float4* __restrict__ out_var)
{
    int wv   = (blockIdx.x * 256 + threadIdx.x) >> 6;  // b*D4 + d4
    int lane = threadIdx.x & 63;
    int b  = wv >> 8;
    int d4 = wv & (D4 - 1);
    int c0 = 2 * lane, c1 = 2 * lane + 1;
    int ch0 = b * Cn + c0, ch1 = b * Cn + c1;

    St s0, s1;
    s0.n = agg_n[ch0]; s0.m = agg_mean[(size_t)ch0 * D4 + d4]; s0.s = agg_m2[(size_t)ch0 * D4 + d4];
    s1.n = agg_n[ch1]; s1.m = agg_mean[(size_t)ch1 * D4 + d4]; s1.s = agg_m2[(size_t)ch1 * D4 + d4];

    St incl = chan_merge(s0, s1);             // per-lane pair stat
    #pragma unroll
    for (int off = 1; off < 64; off <<= 1) {
        St t = shfl_up_st(incl, off);
        if (lane >= off) incl = chan_merge(t, incl);
    }
    St epp = shfl_up_st(incl, 1);             // exclusive pair prefix
    if (lane == 0) {
        epp.n = 0.f;
        epp.m = {0.f, 0.f, 0.f, 0.f};
        epp.s = {0.f, 0.f, 0.f, 0.f};
    }

    float np = (float)prev_count[b];          // >= 1 always
    St P;
    P.n = np;
    P.m = prev_mean[b * D4 + d4];
    float4 vp = prev_var[b * D4 + d4];
    P.s = {vp.x * np, vp.y * np, vp.z * np, vp.w * np};

    St pref0 = chan_merge(P, epp);
    St pref1 = chan_merge(pref0, s0);

    pref_mean[(size_t)ch0 * D4 + d4] = pref0.m; pref_m2[(size_t)ch0 * D4 + d4] = pref0.s;
    pref_mean[(size_t)ch1 * D4 + d4] = pref1.m; pref_m2[(size_t)ch1 * D4 + d4] = pref1.s;
    if (d4 == 0) {
        pref_n[ch0] = pref0.n;
        pref_n[ch1] = pref1.n;
    }

    if (lane == 63) {
        St tot = chan_merge(P, incl);
        out_mean[b * D4 + d4] = tot.m;
        float rn = 1.f / tot.n;
        out_var[b * D4 + d4] = {tot.s.x * rn, tot.s.y * rn, tot.s.z * rn, tot.s.w * rn};
        if (d4 == 0) out_count[b] = tot.n;
    }
}

// ---- K3: replay + emit ------------------------------------------------------
__global__ __launch_bounds__(256) void tn_emit(
    const float* __restrict__ x, const int* __restrict__ mask,
    const float* __restrict__ weight, const float* __restrict__ bias,
    const float4* __restrict__ pref_mean, const float4* __restrict__ pref_m2,
    const float* __restrict__ pref_n, float* __restrict__ y)
{
    int bc = blockIdx.x;
    int d4 = threadIdx.x;
    size_t gbase = (size_t)bc * CLn * Dn;
    const float4* xp = (const float4*)(x + gbase) + d4;
    f32x4*        yp = (f32x4*)(y + gbase) + d4;
    const int4*   mp = (const int4*)(mask + bc * CLn);

    int4 mrow[CLn / 4];
    #pragma unroll
    for (int i = 0; i < CLn / 4; ++i) mrow[i] = mp[i];
    const int* mr = (const int*)mrow;

    float  n    = pref_n[bc];
    float4 mean = pref_mean[(size_t)bc * D4 + d4];   // contiguous
    float4 M2   = pref_m2  [(size_t)bc * D4 + d4];
    const float4 w4 = ((const float4*)weight)[d4];
    const float4 b4 = ((const float4*)bias)[d4];
    float gx = w4.x + 1.f, gy = w4.y + 1.f, gz = w4.z + 1.f, gw = w4.w + 1.f;

    #pragma unroll 4
    for (int i = 0; i < CLn; ++i) {
        f32x4 yv = {0.f, 0.f, 0.f, 0.f};
        if (mr[i] == 0) {                     // block-uniform: skip masked rows
            float4 xv = xp[(size_t)i * D4];
            n += 1.f;
            float rn = 1.f / n;
            float dx, d2;
            dx = xv.x - mean.x; mean.x += dx * rn; d2 = xv.x - mean.x;
            M2.x += dx * d2; yv.x = gx * d2 * rsqrtf(M2.x * rn + EPSf) + b4.x;
            dx = xv.y - mean.y; mean.y += dx * rn; d2 = xv.y - mean.y;
            M2.y += dx * d2; yv.y = gy * d2 * rsqrtf(M2.y * rn + EPSf) + b4.y;
            dx = xv.z - mean.z; mean.z += dx * rn; d2 = xv.z - mean.z;
            M2.z += dx * d2; yv.z = gz * d2 * rsqrtf(M2.z * rn + EPSf) + b4.z;
            dx = xv.w - mean.w; mean.w += dx * rn; d2 = xv.w - mean.w;
            M2.w += dx * d2; yv.w = gw * d2 * rsqrtf(M2.w * rn + EPSf) + b4.w;
        }
        // write-once stream: nontemporal so y doesn't evict x/stats from L2/L3
        __builtin_nontemporal_store(yv, &yp[(size_t)i * D4]);
    }
}

extern "C" void kernel_launch(void* const* d_in, const int* in_sizes, int n_in,
                              void* d_out, int out_size, void* d_ws, size_t ws_size,
                              hipStream_t stream)
{
    const float* x          = (const float*)d_in[0];
    const int*   prev_count = (const int*)d_in[1];
    const float* prev_mean  = (const float*)d_in[2];
    const float* prev_var   = (const float*)d_in[3];
    const float* weight     = (const float*)d_in[4];
    const float* bias       = (const float*)d_in[5];
    const int*   mask       = (const int*)d_in[6];   // bool arrives as int32

    // outputs: y [B*L*D], count [B], mean [B*D], var [B*D] (all fp32, concat)
    float* y         = (float*)d_out;
    float* out_count = y + (size_t)Bn * Ln * Dn;
    float* out_mean  = out_count + Bn;
    float* out_var   = out_mean + (size_t)Bn * Dn;

    // workspace (~33.6 MB): agg/pref payloads [NCH*D4] float4 + per-chunk n
    float4* agg_mean  = (float4*)d_ws;
    float4* agg_m2    = agg_mean  + (size_t)NCH * D4;
    float4* pref_mean = agg_m2    + (size_t)NCH * D4;
    float4* pref_m2   = pref_mean + (size_t)NCH * D4;
    float*  agg_n     = (float*)(pref_m2 + (size_t)NCH * D4);
    float*  pref_n    = agg_n + NCH;

    tn_chunk_stats<<<NCH, 256, 0, stream>>>(x, mask, agg_mean, agg_m2, agg_n);
    tn_scan<<<(Bn * D4) / 4, 256, 0, stream>>>(
        prev_count, (const float4*)prev_mean, (const float4*)prev_var,
        agg_mean, agg_m2, agg_n, pref_mean, pref_m2, pref_n,
        out_count, (float4*)out_mean, (float4*)out_var);
    tn_emit<<<NCH, 256, 0, stream>>>(
        x, mask, weight, bias, pref_mean, pref_m2, pref_n, y);
}

// Round 7
// 447.678 us; speedup vs baseline: 3.2110x; 1.1215x over previous
//
#include <hip/hip_runtime.h>

// TimestepNorm: B=16, L=4096, D=1024, fp32 — 3-kernel chunk-scan, no atomics.
// Cn=64 chunks of 64 rows: stats traffic halved vs Cn=128 (67 MB total),
// K2 chain = 64 chunks = exactly one lane per chunk (no pair stage).
// K1: per-chunk Welford, mask in LDS (block-uniform branch, no VGPR array),
//     x read NORMAL (populates L3 for K3), skip masked rows (~134MB read).
// K2: Kogge-Stone wave scan, one wave per (b,d4) chain (4096 waves, full GPU).
// K3: replay from exclusive prefix; x read NONTEMPORAL (last use), y stored
//     NONTEMPORAL (write-once 268MB stream must not evict x from L3).

#define Bn 16
#define Ln 4096
#define Dn 1024
#define D4 (Dn / 4)     // 256 float4 groups
#define Cn 64
#define CLn (Ln / Cn)   // 64 rows per chunk
#define NCH (Bn * Cn)   // 1024 chunks
#define EPSf 1e-5f

typedef float f32x4 __attribute__((ext_vector_type(4)));   // native vec for nt ops

struct St { float n; float4 m; float4 s; };   // count, mean, M2 (= n*var)

__device__ __forceinline__ St chan_merge(const St& A, const St& B) {
    St R;
    R.n = A.n + B.n;
    float wB = B.n / fmaxf(R.n, 1.f);          // identity-safe: n==0 on either side
    float sc = A.n * wB;
    float dx = B.m.x - A.m.x, dy = B.m.y - A.m.y,
          dz = B.m.z - A.m.z, dw = B.m.w - A.m.w;
    R.m.x = A.m.x + dx * wB; R.m.y = A.m.y + dy * wB;
    R.m.z = A.m.z + dz * wB; R.m.w = A.m.w + dw * wB;
    R.s.x = A.s.x + B.s.x + dx * dx * sc; R.s.y = A.s.y + B.s.y + dy * dy * sc;
    R.s.z = A.s.z + B.s.z + dz * dz * sc; R.s.w = A.s.w + B.s.w + dw * dw * sc;
    return R;
}

__device__ __forceinline__ St shfl_up_st(const St& v, int delta) {
    St r;
    r.n   = __shfl_up(v.n,   delta, 64);
    r.m.x = __shfl_up(v.m.x, delta, 64); r.m.y = __shfl_up(v.m.y, delta, 64);
    r.m.z = __shfl_up(v.m.z, delta, 64); r.m.w = __shfl_up(v.m.w, delta, 64);
    r.s.x = __shfl_up(v.s.x, delta, 64); r.s.y = __shfl_up(v.s.y, delta, 64);
    r.s.z = __shfl_up(v.s.z, delta, 64); r.s.w = __shfl_up(v.s.w, delta, 64);
    return r;
}

// ---- K1: per-chunk Welford --------------------------------------------------
__global__ __launch_bounds__(256) void tn_chunk_stats(
    const float* __restrict__ x, const int* __restrict__ mask,
    float4* __restrict__ agg_mean, float4* __restrict__ agg_m2,
    float* __restrict__ agg_n)
{
    int bc = blockIdx.x;                      // b*Cn + c
    int d4 = threadIdx.x;
    __shared__ int smask[CLn];
    if (threadIdx.x < CLn) smask[threadIdx.x] = mask[bc * CLn + threadIdx.x];
    __syncthreads();

    const float4* xp = (const float4*)(x + (size_t)bc * CLn * Dn) + d4;

    St A; A.n = 0.f; A.m = {0.f, 0.f, 0.f, 0.f}; A.s = {0.f, 0.f, 0.f, 0.f};
    #pragma unroll 4
    for (int i = 0; i < CLn; ++i) {
        if (smask[i] == 0) {                  // block-uniform; masked rows never read
            float4 xv = xp[(size_t)i * D4];
            A.n += 1.f;
            float rn = 1.f / A.n;
            float dx;
            dx = xv.x - A.m.x; A.m.x += dx * rn; A.s.x += dx * (xv.x - A.m.x);
            dx = xv.y - A.m.y; A.m.y += dx * rn; A.s.y += dx * (xv.y - A.m.y);
            dx = xv.z - A.m.z; A.m.z += dx * rn; A.s.z += dx * (xv.z - A.m.z);
            dx = xv.w - A.m.w; A.m.w += dx * rn; A.s.w += dx * (xv.w - A.m.w);
        }
    }
    agg_mean[(size_t)bc * D4 + d4] = A.m;     // contiguous 4KB per chunk
    agg_m2  [(size_t)bc * D4 + d4] = A.s;
    if (d4 == 0) agg_n[bc] = A.n;
}

// ---- K2: Kogge-Stone wave scan, one wave per (b,d4) chain, lane = chunk -----
// 4096 waves = 1024 blocks x 4.
__global__ __launch_bounds__(256) void tn_scan(
    const int* __restrict__ prev_count, const float4* __restrict__ prev_mean,
    const float4* __restrict__ prev_var,
    const float4* __restrict__ agg_mean, const float4* __restrict__ agg_m2,
    const float* __restrict__ agg_n,
    float4* __restrict__ pref_mean, float4* __restrict__ pref_m2,
    float* __restrict__ pref_n,
    float* __restrict__ out_count, float4* __restrict__ out_mean,
    float4* __restrict__ out_var)
{
    int wv   = (blockIdx.x * 256 + threadIdx.x) >> 6;  // b*D4 + d4
    int lane = threadIdx.x & 63;                       // == chunk c
    int b  = wv >> 8;
    int d4 = wv & (D4 - 1);
    int ch = b * Cn + lane;

    St s0;
    s0.n = agg_n[ch];
    s0.m = agg_mean[(size_t)ch * D4 + d4];
    s0.s = agg_m2  [(size_t)ch * D4 + d4];

    St incl = s0;
    #pragma unroll
    for (int off = 1; off < 64; off <<= 1) {
        St t = shfl_up_st(incl, off);
        if (lane >= off) incl = chan_merge(t, incl);
    }
    St excl = shfl_up_st(incl, 1);            // exclusive prefix (chunks only)
    if (lane == 0) {
        excl.n = 0.f;
        excl.m = {0.f, 0.f, 0.f, 0.f};
        excl.s = {0.f, 0.f, 0.f, 0.f};
    }

    float np = (float)prev_count[b];          // >= 1 always
    St P;
    P.n = np;
    P.m = prev_mean[b * D4 + d4];
    float4 vp = prev_var[b * D4 + d4];
    P.s = {vp.x * np, vp.y * np, vp.z * np, vp.w * np};

    St pref = chan_merge(P, excl);            // exclusive incl. prev carry

    pref_mean[(size_t)ch * D4 + d4] = pref.m;
    pref_m2  [(size_t)ch * D4 + d4] = pref.s;
    if (d4 == 0) pref_n[ch] = pref.n;

    if (lane == 63) {
        St tot = chan_merge(P, incl);
        out_mean[b * D4 + d4] = tot.m;
        float rn = 1.f / tot.n;
        out_var[b * D4 + d4] = {tot.s.x * rn, tot.s.y * rn, tot.s.z * rn, tot.s.w * rn};
        if (d4 == 0) out_count[b] = tot.n;
    }
}

// ---- K3: replay + emit ------------------------------------------------------
__global__ __launch_bounds__(256) void tn_emit(
    const float* __restrict__ x, const int* __restrict__ mask,
    const float* __restrict__ weight, const float* __restrict__ bias,
    const float4* __restrict__ pref_mean, const float4* __restrict__ pref_m2,
    const float* __restrict__ pref_n, float* __restrict__ y)
{
    int bc = blockIdx.x;
    int d4 = threadIdx.x;
    __shared__ int smask[CLn];
    if (threadIdx.x < CLn) smask[threadIdx.x] = mask[bc * CLn + threadIdx.x];
    __syncthreads();

    size_t gbase = (size_t)bc * CLn * Dn;
    const f32x4* xp = (const f32x4*)(x + gbase) + d4;
    f32x4*       yp = (f32x4*)(y + gbase) + d4;

    float  n    = pref_n[bc];
    float4 mean = pref_mean[(size_t)bc * D4 + d4];   // contiguous
    float4 M2   = pref_m2  [(size_t)bc * D4 + d4];
    const float4 w4 = ((const float4*)weight)[d4];
    const float4 b4 = ((const float4*)bias)[d4];
    float gx = w4.x + 1.f, gy = w4.y + 1.f, gz = w4.z + 1.f, gw = w4.w + 1.f;

    #pragma unroll 4
    for (int i = 0; i < CLn; ++i) {
        f32x4 yv = {0.f, 0.f, 0.f, 0.f};
        if (smask[i] == 0) {                  // block-uniform: skip masked rows
            // last use of x: nontemporal read (don't hold it against y stream)
            f32x4 xv = __builtin_nontemporal_load(&xp[(size_t)i * D4]);
            n += 1.f;
            float rn = 1.f / n;
            float dx, d2;
            dx = xv.x - mean.x; mean.x += dx * rn; d2 = xv.x - mean.x;
            M2.x += dx * d2; yv.x = gx * d2 * rsqrtf(M2.x * rn + EPSf) + b4.x;
            dx = xv.y - mean.y; mean.y += dx * rn; d2 = xv.y - mean.y;
            M2.y += dx * d2; yv.y = gy * d2 * rsqrtf(M2.y * rn + EPSf) + b4.y;
            dx = xv.z - mean.z; mean.z += dx * rn; d2 = xv.z - mean.z;
            M2.z += dx * d2; yv.z = gz * d2 * rsqrtf(M2.z * rn + EPSf) + b4.z;
            dx = xv.w - mean.w; mean.w += dx * rn; d2 = xv.w - mean.w;
            M2.w += dx * d2; yv.w = gw * d2 * rsqrtf(M2.w * rn + EPSf) + b4.w;
        }
        // write-once stream: nontemporal so y doesn't evict x/stats from L2/L3
        __builtin_nontemporal_store(yv, &yp[(size_t)i * D4]);
    }
}

extern "C" void kernel_launch(void* const* d_in, const int* in_sizes, int n_in,
                              void* d_out, int out_size, void* d_ws, size_t ws_size,
                              hipStream_t stream)
{
    const float* x          = (const float*)d_in[0];
    const int*   prev_count = (const int*)d_in[1];
    const float* prev_mean  = (const float*)d_in[2];
    const float* prev_var   = (const float*)d_in[3];
    const float* weight     = (const float*)d_in[4];
    const float* bias       = (const float*)d_in[5];
    const int*   mask       = (const int*)d_in[6];   // bool arrives as int32

    // outputs: y [B*L*D], count [B], mean [B*D], var [B*D] (all fp32, concat)
    float* y         = (float*)d_out;
    float* out_count = y + (size_t)Bn * Ln * Dn;
    float* out_mean  = out_count + Bn;
    float* out_var   = out_mean + (size_t)Bn * Dn;

    // workspace (~16.8 MB): agg/pref payloads [NCH*D4] float4 + per-chunk n
    float4* agg_mean  = (float4*)d_ws;
    float4* agg_m2    = agg_mean  + (size_t)NCH * D4;
    float4* pref_mean = agg_m2    + (size_t)NCH * D4;
    float4* pref_m2   = pref_mean + (size_t)NCH * D4;
    float*  agg_n     = (float*)(pref_m2 + (size_t)NCH * D4);
    float*  pref_n    = agg_n + NCH;

    tn_chunk_stats<<<NCH, 256, 0, stream>>>(x, mask, agg_mean, agg_m2, agg_n);
    tn_scan<<<(Bn * D4 * 64) / 256, 256, 0, stream>>>(
        prev_count, (const float4*)prev_mean, (const float4*)prev_var,
        agg_mean, agg_m2, agg_n, pref_mean, pref_m2, pref_n,
        out_count, (float4*)out_mean, (float4*)out_var);
    tn_emit<<<NCH, 256, 0, stream>>>(
        x, mask, weight, bias, pref_mean, pref_m2, pref_n, y);
}